// Round 9
// baseline (221.191 us; speedup 1.0000x reference)
//
#include <hip/hip_runtime.h>
#include <hip/hip_bf16.h>
#include <stdint.h>

typedef __bf16 bf16x8 __attribute__((ext_vector_type(8)));
typedef _Float16 f16x8 __attribute__((ext_vector_type(8)));
typedef _Float16 f16x2 __attribute__((ext_vector_type(2)));
typedef float f32x4 __attribute__((ext_vector_type(4)));
typedef unsigned short u16;
typedef unsigned int u32;

struct __align__(8) us4 { u16 x, y, z, w; };

#define LOG2E 1.44269504088896f
#define QSCALE (0.125f * LOG2E)

// async global->LDS, 16B per lane. LDS dest = wave-uniform base + lane*16.
__device__ __forceinline__ void async_load16(const void* g, void* l) {
    __builtin_amdgcn_global_load_lds(
        (const __attribute__((address_space(1))) u32*)(uintptr_t)g,
        (__attribute__((address_space(3))) u32*)(u32)(uintptr_t)l,
        16, 0, 0);
}

__device__ __forceinline__ u16 f2bfbits(float f) {
    __bf16 h = (__bf16)f;
    return __builtin_bit_cast(u16, h);
}
__device__ __forceinline__ u16 f2hbits(float f) {
    _Float16 h = (_Float16)f;
    return __builtin_bit_cast(u16, h);
}
__device__ __forceinline__ f16x2 pkrtz(float a, float b) {
    return __builtin_bit_cast(f16x2, __builtin_amdgcn_cvt_pkrtz(a, b));
}

// Build a bf16x8 fragment from a swizzled fp32 LDS tile.
__device__ __forceinline__ bf16x8 frag_from_f32(const float* T, int row, int kkq2, int id) {
    const float4 lo = *(const float4*)&T[row * 64 + (((kkq2) ^ id) << 2)];
    const float4 hi = *(const float4*)&T[row * 64 + (((kkq2 + 1) ^ id) << 2)];
    bf16x8 f;
    f[0] = (__bf16)lo.x; f[1] = (__bf16)lo.y; f[2] = (__bf16)lo.z; f[3] = (__bf16)lo.w;
    f[4] = (__bf16)hi.x; f[5] = (__bf16)hi.y; f[6] = (__bf16)hi.z; f[7] = (__bf16)hi.w;
    return f;
}

// Fused Q/K/V projections reading fp32 x/ctx/W directly (inline cvt).
__global__ __launch_bounds__(256) void proj_qkv(
    const float* __restrict__ x, const float* __restrict__ ctx,
    const float* __restrict__ Wq, const float* __restrict__ Wk,
    const float* __restrict__ Wv,
    u16* __restrict__ q, u16* __restrict__ k2, u16* __restrict__ vT) {
    __shared__ float As[128 * 64];
    __shared__ float Bs[128 * 64];
    const int tid = threadIdx.x;
    const int w = tid >> 6, lane = tid & 63, quad = lane >> 4, id = lane & 15;
    const int wr = (w >> 1) * 64, wc = (w & 1) * 64;
    const int arow = lane >> 4;
    const int swzcb = (lane & 15) ^ (w * 4 + arow);

    const int bid = blockIdx.x;
    const float *A, *Bm;
    int mtile, ntile, mode;
    if (bid < 256) {
        mode = 0; A = x; Bm = Wq;
        mtile = (bid >> 3) * 128; ntile = (bid & 7) * 128;
    } else if (bid < 384) {
        int s2 = bid - 256;
        mode = 1; A = ctx; Bm = Wk;
        mtile = (s2 >> 1) * 128; ntile = (s2 & 1) * 128;
    } else {
        int s2 = bid - 384;
        mode = 2; A = ctx; Bm = Wv;
        mtile = (s2 >> 1) * 128; ntile = (s2 & 1) * 128;
    }

    f32x4 acc[4][4];
#pragma unroll
    for (int i = 0; i < 4; i++)
#pragma unroll
        for (int j = 0; j < 4; j++) acc[i][j] = (f32x4){0.f, 0.f, 0.f, 0.f};

    for (int k0 = 0; k0 < 1024; k0 += 64) {
        __syncthreads();
#pragma unroll
        for (int is = 0; is < 8; is++) {
            int base = is * 16 + w * 4;
            async_load16(A + (size_t)(mtile + base + arow) * 1024 + k0 + swzcb * 4,
                         &As[base * 64]);
        }
#pragma unroll
        for (int is = 0; is < 8; is++) {
            int base = is * 16 + w * 4;
            async_load16(Bm + (size_t)(ntile + base + arow) * 1024 + k0 + swzcb * 4,
                         &Bs[base * 64]);
        }
        __syncthreads();
#pragma unroll
        for (int kk = 0; kk < 2; kk++) {
            const int kkq2 = kk * 8 + quad * 2;
            bf16x8 af[4], bfr[4];
#pragma unroll
            for (int i = 0; i < 4; i++)
                af[i] = frag_from_f32(As, wr + i * 16 + id, kkq2, id);
#pragma unroll
            for (int j = 0; j < 4; j++)
                bfr[j] = frag_from_f32(Bs, wc + j * 16 + id, kkq2, id);
#pragma unroll
            for (int i = 0; i < 4; i++)
#pragma unroll
                for (int j = 0; j < 4; j++)
                    acc[i][j] = __builtin_amdgcn_mfma_f32_16x16x32_bf16(af[i], bfr[j], acc[i][j], 0, 0, 0);
        }
    }

#pragma unroll
    for (int i = 0; i < 4; i++)
#pragma unroll
        for (int j = 0; j < 4; j++) {
            int mbase = mtile + wr + i * 16 + quad * 4;
            int n = ntile + wc + j * 16 + id;
            if (mode == 2) {
                int b = mbase >> 11, t = mbase & 2047;
                int g = n >> 6, d = n & 63;
                us4 pk;
                pk.x = f2hbits(acc[i][j][0]);
                pk.y = f2hbits(acc[i][j][1]);
                pk.z = f2hbits(acc[i][j][2]);
                pk.w = f2hbits(acc[i][j][3]);
                *(us4*)&vT[((size_t)((b << 2) + g) * 64 + d) * 2048 + t] = pk;
            } else if (mode == 1) {
#pragma unroll
                for (int r = 0; r < 4; r++) {
                    int m = mbase + r;
                    int b = m >> 11, t = m & 2047;
                    int g = n >> 6, d = n & 63;
                    k2[((size_t)((b << 2) + g) * 2048 + t) * 64 + d] = f2bfbits(acc[i][j][r]);
                }
            } else {
#pragma unroll
                for (int r = 0; r < 4; r++)
                    q[(size_t)(mbase + r) * 1024 + n] = f2bfbits(acc[i][j][r] * QSCALE);
            }
        }
}

// Output projection: out(f32) = o(bf16) @ Wo(fp32)^T.
__global__ __launch_bounds__(256) void gemm_out(const u16* __restrict__ A,
                                                const float* __restrict__ Bm,
                                                float* __restrict__ C) {
    __shared__ u16 As[128 * 64];
    __shared__ float Bs[128 * 64];
    const int tid = threadIdx.x;
    const int w = tid >> 6, lane = tid & 63, quad = lane >> 4, id = lane & 15;
    const int mtile = blockIdx.y * 128, ntile = blockIdx.x * 128;
    const int wr = (w >> 1) * 64, wc = (w & 1) * 64;
    const int arow = lane >> 4;
    const int swzcb = (lane & 15) ^ (w * 4 + arow);
    const int stgswz8 = ((lane & 7) ^ (lane >> 3)) * 8;

    f32x4 acc[4][4];
#pragma unroll
    for (int i = 0; i < 4; i++)
#pragma unroll
        for (int j = 0; j < 4; j++) acc[i][j] = (f32x4){0.f, 0.f, 0.f, 0.f};

    for (int k0 = 0; k0 < 1024; k0 += 64) {
        __syncthreads();
#pragma unroll
        for (int is = 0; is < 4; is++) {
            int base = is * 32 + w * 8;
            async_load16(A + (size_t)(mtile + base + (lane >> 3)) * 1024 + k0 + stgswz8,
                         &As[base * 64]);
        }
#pragma unroll
        for (int is = 0; is < 8; is++) {
            int base = is * 16 + w * 4;
            async_load16(Bm + (size_t)(ntile + base + arow) * 1024 + k0 + swzcb * 4,
                         &Bs[base * 64]);
        }
        __syncthreads();
#pragma unroll
        for (int kk = 0; kk < 2; kk++) {
            const int kkq2 = kk * 8 + quad * 2;
            bf16x8 af[4], bfr[4];
#pragma unroll
            for (int i = 0; i < 4; i++) {
                int row = wr + i * 16 + id;
                af[i] = *(const bf16x8*)&As[row * 64 + (((kk * 4 + quad) ^ (id & 7)) * 8)];
            }
#pragma unroll
            for (int j = 0; j < 4; j++)
                bfr[j] = frag_from_f32(Bs, wc + j * 16 + id, kkq2, id);
#pragma unroll
            for (int i = 0; i < 4; i++)
#pragma unroll
                for (int j = 0; j < 4; j++)
                    acc[i][j] = __builtin_amdgcn_mfma_f32_16x16x32_bf16(af[i], bfr[j], acc[i][j], 0, 0, 0);
        }
    }

#pragma unroll
    for (int i = 0; i < 4; i++)
#pragma unroll
        for (int j = 0; j < 4; j++) {
            int mbase = mtile + wr + i * 16 + quad * 4;
            int n = ntile + wc + j * 16 + id;
#pragma unroll
            for (int r = 0; r < 4; r++)
                C[(size_t)(mbase + r) * 1024 + n] = acc[i][j][r];
        }
}

// Split-T flash attention, no-max softmax, register-only fp16 P path.
// Grid 1024: xcd(8) x bgi(2) x th(2) x h-rep(4) x s-tile(8). Each block does
// half the T range (16 chunks) and writes UN-normalized O-partial (f32) and
// l-partial; combine_kernel merges the two halves (partials are additive
// because there is no running max). 4 blocks/CU -> 16 waves/CU.
__global__ __launch_bounds__(256, 4) void attn_kernel(const u16* __restrict__ q,
                                                      const u16* __restrict__ k2,
                                                      const u16* __restrict__ vT,
                                                      float* __restrict__ opart,
                                                      float* __restrict__ lpart) {
    __shared__ u16 Ks[2][64 * 64];
    __shared__ u16 Vt[2][64 * 64];
    const int tid = threadIdx.x;
    const int w = tid >> 6, lane = tid & 63, quad = lane >> 4, id = lane & 15;

    const int bid = blockIdx.x;
    const int xcd = bid & 7, slot = bid >> 3;          // slot 0..127
    const int bg = xcd * 2 + (slot >> 6);              // 2 (b,g) per XCD
    const int inner = slot & 63;
    const int th = inner >> 5;                          // T-half
    const int hs = inner & 31;
    const int b = bg >> 2, g = bg & 3;
    const int h = g * 4 + (hs >> 3);
    const int s0 = (hs & 7) * 128;
    const int tstart = th * 1024;

    const int stgswz = (((lane & 7) ^ (lane >> 3) ^ ((w & 1) << 2))) * 8;
    int kfkey[2];
#pragma unroll
    for (int c = 0; c < 2; c++)
        kfkey[c] = (id & 3) | (((c ^ ((id >> 2) & 1)) & 1) << 2);
    const int vkey = (id & 7) ^ (((id >> 3) & 1) << 2);
    const int trow_base = ((id & 12) << 1) + (id & 3);

    bf16x8 qf[2][2];
#pragma unroll
    for (int rb = 0; rb < 2; rb++) {
        const size_t base = ((size_t)(b * 1024 + s0 + w * 32 + rb * 16 + id)) * 1024 + h * 64;
        qf[rb][0] = *(const bf16x8*)&q[base + quad * 8];
        qf[rb][1] = *(const bf16x8*)&q[base + 32 + quad * 8];
    }

    f16x8 ones;
#pragma unroll
    for (int i = 0; i < 8; i++) ones[i] = (_Float16)1.0f;

    f32x4 acc[2][4], accl[2];
#pragma unroll
    for (int rb = 0; rb < 2; rb++) {
        accl[rb] = (f32x4){0.f, 0.f, 0.f, 0.f};
#pragma unroll
        for (int i = 0; i < 4; i++) acc[rb][i] = (f32x4){0.f, 0.f, 0.f, 0.f};
    }

    // loop-carried staging pointers (advance by constant strides per chunk)
    const u16* kp = k2 + ((size_t)(b * 4 + g)) * 2048 * 64
                  + (size_t)(tstart + w * 8 + (lane >> 3)) * 64 + stgswz;
    const u16* vp = vT + ((size_t)(b * 4 + g)) * 64 * 2048
                  + (size_t)(w * 8 + (lane >> 3)) * 2048 + tstart + stgswz;

    auto stage = [&](int buf) {
        async_load16(kp,             &Ks[buf][(w * 8) * 64]);
        async_load16(kp + 32 * 64,   &Ks[buf][(32 + w * 8) * 64]);
        async_load16(vp,             &Vt[buf][(w * 8) * 64]);
        async_load16(vp + 32 * 2048, &Vt[buf][(32 + w * 8) * 64]);
        kp += 64 * 64;
        vp += 64;
    };

    auto process = [&](const u16* Ksb, const u16* Vtb) {
        f32x4 s[2][2][2];
#pragma unroll
        for (int kk = 0; kk < 2; kk++)
#pragma unroll
            for (int P = 0; P < 2; P++)
#pragma unroll
                for (int c = 0; c < 2; c++) {
                    int trow = P * 32 + trow_base + c * 4;
                    bf16x8 kf = *(const bf16x8*)&Ksb[trow * 64 + (((kk * 4 + quad) ^ kfkey[c]) * 8)];
#pragma unroll
                    for (int rb = 0; rb < 2; rb++)
                        s[rb][P][c] = __builtin_amdgcn_mfma_f32_16x16x32_bf16(
                            kf, qf[rb][kk],
                            kk ? s[rb][P][c] : (f32x4){0.f, 0.f, 0.f, 0.f}, 0, 0, 0);
                }

        f16x8 pa[2][2];
        union PU { f16x8 v; f16x2 h[4]; };
#pragma unroll
        for (int rb = 0; rb < 2; rb++)
#pragma unroll
            for (int P = 0; P < 2; P++) {
                PU u;
#pragma unroll
                for (int c = 0; c < 2; c++) {
                    float e0 = __builtin_exp2f(s[rb][P][c][0]);
                    float e1 = __builtin_exp2f(s[rb][P][c][1]);
                    float e2 = __builtin_exp2f(s[rb][P][c][2]);
                    float e3 = __builtin_exp2f(s[rb][P][c][3]);
                    u.h[c * 2 + 0] = pkrtz(e0, e1);
                    u.h[c * 2 + 1] = pkrtz(e2, e3);
                }
                pa[rb][P] = u.v;
            }

#pragma unroll
        for (int P = 0; P < 2; P++) {
#pragma unroll
            for (int db = 0; db < 4; db++) {
                f16x8 vf = *(const f16x8*)&Vtb[(db * 16 + id) * 64 + (((P * 4 + quad) ^ vkey) * 8)];
#pragma unroll
                for (int rb = 0; rb < 2; rb++)
                    acc[rb][db] = __builtin_amdgcn_mfma_f32_16x16x32_f16(pa[rb][P], vf, acc[rb][db], 0, 0, 0);
            }
#pragma unroll
            for (int rb = 0; rb < 2; rb++)
                accl[rb] = __builtin_amdgcn_mfma_f32_16x16x32_f16(pa[rb][P], ones, accl[rb], 0, 0, 0);
        }
    };

    stage(0);
    __syncthreads();

#pragma unroll 1
    for (int it = 0; it < 8; ++it) {
        stage(1);                      // chunk 2it+1, overlaps buf0 compute
        process(Ks[0], Vt[0]);
        __syncthreads();
        if (it != 7) stage(0);         // chunk 2it+2, overlaps buf1 compute
        process(Ks[1], Vt[1]);
        __syncthreads();
    }

    // store UN-normalized partials
    float* op = opart + (size_t)th * (4096 * 1024);
    float* lp = lpart + (size_t)th * (4096 * 16);
#pragma unroll
    for (int rb = 0; rb < 2; rb++)
#pragma unroll
        for (int db = 0; db < 4; db++)
#pragma unroll
            for (int r = 0; r < 4; r++) {
                int srow = s0 + w * 32 + rb * 16 + quad * 4 + r;
                op[((size_t)(b * 1024 + srow)) * 1024 + h * 64 + db * 16 + id] = acc[rb][db][r];
            }
    if (id == 0) {
#pragma unroll
        for (int rb = 0; rb < 2; rb++)
#pragma unroll
            for (int r = 0; r < 4; r++) {
                int srow = s0 + w * 32 + rb * 16 + quad * 4 + r;
                lp[(size_t)(b * 1024 + srow) * 16 + h] = accl[rb][r];
            }
    }
}

// Combine T-halves: o_bf16[m][n] = (O0+O1)[m][n] / (l0+l1)[m][n>>6].
// 8 floats per thread (never crosses a head boundary).
__global__ __launch_bounds__(256) void combine_kernel(const float* __restrict__ opart,
                                                      const float* __restrict__ lpart,
                                                      u16* __restrict__ o) {
    int i = blockIdx.x * 256 + threadIdx.x;   // 0 .. 524287
    int m = i >> 7;
    int n0 = (i & 127) * 8;
    int hh = n0 >> 6;
    float inv = 1.0f / (lpart[(size_t)m * 16 + hh] + lpart[4096 * 16 + (size_t)m * 16 + hh]);
    const float* p0 = opart + (size_t)m * 1024 + n0;
    const float* p1 = p0 + (size_t)4096 * 1024;
    float4 a0 = *(const float4*)p0, a1 = *(const float4*)(p0 + 4);
    float4 b0 = *(const float4*)p1, b1 = *(const float4*)(p1 + 4);
    us4 lo, hi;
    lo.x = f2bfbits((a0.x + b0.x) * inv); lo.y = f2bfbits((a0.y + b0.y) * inv);
    lo.z = f2bfbits((a0.z + b0.z) * inv); lo.w = f2bfbits((a0.w + b0.w) * inv);
    hi.x = f2bfbits((a1.x + b1.x) * inv); hi.y = f2bfbits((a1.y + b1.y) * inv);
    hi.z = f2bfbits((a1.z + b1.z) * inv); hi.w = f2bfbits((a1.w + b1.w) * inv);
    *(us4*)&o[(size_t)m * 1024 + n0] = lo;
    *(us4*)&o[(size_t)m * 1024 + n0 + 4] = hi;
}

extern "C" void kernel_launch(void* const* d_in, const int* in_sizes, int n_in,
                              void* d_out, int out_size, void* d_ws, size_t ws_size,
                              hipStream_t stream) {
    (void)in_sizes; (void)n_in; (void)out_size; (void)ws_size;
    const float* x   = (const float*)d_in[0];
    const float* ctx = (const float*)d_in[1];
    const float* Wq  = (const float*)d_in[2];
    const float* Wk  = (const float*)d_in[3];
    const float* Wv  = (const float*)d_in[4];
    const float* Wo  = (const float*)d_in[5];
    float* out = (float*)d_out;

    // workspace layout (bytes): q 8M | k2 4M | vT 4M | o 8M | opart 32M | lpart 0.5M
    u16*   q     = (u16*)d_ws;
    u16*   k2    = q + 4096 * 1024;
    u16*   vT    = k2 + 4 * 4 * 2048 * 64;
    u16*   o     = vT + 4 * 4 * 64 * 2048;
    float* opart = (float*)(o + 4096 * 1024);
    float* lpart = opart + 2 * 4096 * 1024;

    proj_qkv<<<512, 256, 0, stream>>>(x, ctx, Wq, Wk, Wv, q, k2, vT);
    attn_kernel<<<1024, 256, 0, stream>>>(q, k2, vT, opart, lpart);
    combine_kernel<<<2048, 256, 0, stream>>>(opart, lpart, o);
    gemm_out<<<dim3(8, 32), 256, 0, stream>>>(o, Wo, out);
}

// Round 10
// 205.505 us; speedup vs baseline: 1.0763x; 1.0763x over previous
//
#include <hip/hip_runtime.h>
#include <hip/hip_bf16.h>
#include <stdint.h>

typedef __bf16 bf16x8 __attribute__((ext_vector_type(8)));
typedef float f32x4 __attribute__((ext_vector_type(4)));
typedef unsigned short u16;
typedef unsigned int u32;

struct __align__(8) us4 { u16 x, y, z, w; };
struct __align__(16) us8 { u16 v[8]; };

#define LOG2E 1.44269504088896f
#define QSCALE (0.125f * LOG2E)

// async global->LDS, 16B per lane. LDS dest = wave-uniform base + lane*16.
__device__ __forceinline__ void async_load16(const void* g, void* l) {
    __builtin_amdgcn_global_load_lds(
        (const __attribute__((address_space(1))) u32*)(uintptr_t)g,
        (__attribute__((address_space(3))) u32*)(u32)(uintptr_t)l,
        16, 0, 0);
}

__device__ __forceinline__ u16 f2bfbits(float f) {
    __bf16 h = (__bf16)f;   // RNE fptrunc
    return __builtin_bit_cast(u16, h);
}

// Single fused fp32->bf16 convert over all 6 inputs. 8 elems/thread.
__global__ __launch_bounds__(256) void convert_all(
    const float* __restrict__ x, const float* __restrict__ ctx,
    const float* __restrict__ wq, const float* __restrict__ wk,
    const float* __restrict__ wv, const float* __restrict__ wo,
    u16* __restrict__ xb, u16* __restrict__ ctxb, u16* __restrict__ wqb,
    u16* __restrict__ wkb, u16* __restrict__ wvb, u16* __restrict__ wob) {
    int i = blockIdx.x * 256 + threadIdx.x;
    const float* s; u16* d; int j;
    if (i < 524288)        { s = x;   d = xb;   j = i; }
    else if (i < 1572864)  { s = ctx; d = ctxb; j = i - 524288; }
    else if (i < 1703936)  { s = wq;  d = wqb;  j = i - 1572864; }
    else if (i < 1736704)  { s = wk;  d = wkb;  j = i - 1703936; }
    else if (i < 1769472)  { s = wv;  d = wvb;  j = i - 1736704; }
    else                   { s = wo;  d = wob;  j = i - 1769472; }
    const float4* sp = (const float4*)s + (size_t)j * 2;
    float4 a = sp[0], b = sp[1];
    us8 o;
    o.v[0] = f2bfbits(a.x); o.v[1] = f2bfbits(a.y);
    o.v[2] = f2bfbits(a.z); o.v[3] = f2bfbits(a.w);
    o.v[4] = f2bfbits(b.x); o.v[5] = f2bfbits(b.y);
    o.v[6] = f2bfbits(b.z); o.v[7] = f2bfbits(b.w);
    *(us8*)(d + (size_t)j * 8) = o;
}

// Fused Q/K/V projections, 128x64 tiles, 1024 blocks (4 blocks/CU).
// bid<512: Q (M=4096,N=1024), epilogue * QSCALE, natural layout.
// bid<768: K -> k2 [((b*4+g)*2048+t)*64+d].  else: V -> vT [((b*4+g)*64+d)*2048+t].
__global__ __launch_bounds__(256, 4) void proj_qkv(
    const u16* __restrict__ xb, const u16* __restrict__ ctxb,
    const u16* __restrict__ Wqb, const u16* __restrict__ Wkb,
    const u16* __restrict__ Wvb,
    u16* __restrict__ q, u16* __restrict__ k2, u16* __restrict__ vT) {
    __shared__ u16 As[128 * 64];
    __shared__ u16 Bs[64 * 64];
    const int tid = threadIdx.x;
    const int w = tid >> 6, lane = tid & 63, quad = lane >> 4, id = lane & 15;
    const int wr = (w >> 1) * 64, wc = (w & 1) * 32;
    const int lrow = lane >> 3, lcol = (lane & 7) * 8;

    const int bid = blockIdx.x;
    const u16 *A, *Bm;
    int mtile, ntile, mode;
    if (bid < 512) {
        mode = 0; A = xb; Bm = Wqb;
        mtile = (bid >> 4) * 128; ntile = (bid & 15) * 64;
    } else if (bid < 768) {
        int s2 = bid - 512;
        mode = 1; A = ctxb; Bm = Wkb;
        mtile = (s2 >> 2) * 128; ntile = (s2 & 3) * 64;
    } else {
        int s2 = bid - 768;
        mode = 2; A = ctxb; Bm = Wvb;
        mtile = (s2 >> 2) * 128; ntile = (s2 & 3) * 64;
    }

    f32x4 acc[4][2];
#pragma unroll
    for (int i = 0; i < 4; i++)
#pragma unroll
        for (int j = 0; j < 2; j++) acc[i][j] = (f32x4){0.f, 0.f, 0.f, 0.f};

    for (int k0 = 0; k0 < 1024; k0 += 64) {
        __syncthreads();
#pragma unroll
        for (int is = 0; is < 4; is++) {
            int r = is * 32 + w * 8 + lrow;
            async_load16(A + (size_t)(mtile + r) * 1024 + k0 + lcol, &As[(is * 32 + w * 8) * 64]);
        }
#pragma unroll
        for (int is = 0; is < 2; is++) {
            int r = is * 32 + w * 8 + lrow;
            async_load16(Bm + (size_t)(ntile + r) * 1024 + k0 + lcol, &Bs[(is * 32 + w * 8) * 64]);
        }
        __syncthreads();
#pragma unroll
        for (int kk = 0; kk < 2; kk++) {
            bf16x8 af[4], bfr[2];
#pragma unroll
            for (int i = 0; i < 4; i++)
                af[i] = *(const bf16x8*)&As[(wr + i * 16 + id) * 64 + kk * 32 + quad * 8];
#pragma unroll
            for (int j = 0; j < 2; j++)
                bfr[j] = *(const bf16x8*)&Bs[(wc + j * 16 + id) * 64 + kk * 32 + quad * 8];
#pragma unroll
            for (int i = 0; i < 4; i++)
#pragma unroll
                for (int j = 0; j < 2; j++)
                    acc[i][j] = __builtin_amdgcn_mfma_f32_16x16x32_bf16(af[i], bfr[j], acc[i][j], 0, 0, 0);
        }
    }

#pragma unroll
    for (int i = 0; i < 4; i++)
#pragma unroll
        for (int j = 0; j < 2; j++) {
            int mbase = mtile + wr + i * 16 + quad * 4;
            int n = ntile + wc + j * 16 + id;
            if (mode == 2) {
                int b = mbase >> 11, t = mbase & 2047;
                int g = n >> 6, d = n & 63;
                us4 pk;
                pk.x = f2bfbits(acc[i][j][0]);
                pk.y = f2bfbits(acc[i][j][1]);
                pk.z = f2bfbits(acc[i][j][2]);
                pk.w = f2bfbits(acc[i][j][3]);
                *(us4*)&vT[((size_t)((b << 2) + g) * 64 + d) * 2048 + t] = pk;
            } else if (mode == 1) {
#pragma unroll
                for (int r = 0; r < 4; r++) {
                    int m = mbase + r;
                    int b = m >> 11, t = m & 2047;
                    int g = n >> 6, d = n & 63;
                    k2[((size_t)((b << 2) + g) * 2048 + t) * 64 + d] = f2bfbits(acc[i][j][r]);
                }
            } else {
#pragma unroll
                for (int r = 0; r < 4; r++)
                    q[(size_t)(mbase + r) * 1024 + n] = f2bfbits(acc[i][j][r] * QSCALE);
            }
        }
}

// Output projection, 128x64 tiles, 512 blocks: out(f32) = o(bf16) @ Wo^T.
__global__ __launch_bounds__(256, 4) void gemm_out(const u16* __restrict__ A,
                                                   const u16* __restrict__ Bm,
                                                   float* __restrict__ C) {
    __shared__ u16 As[128 * 64];
    __shared__ u16 Bs[64 * 64];
    const int tid = threadIdx.x;
    const int w = tid >> 6, lane = tid & 63, quad = lane >> 4, id = lane & 15;
    const int mtile = blockIdx.y * 128, ntile = blockIdx.x * 64;
    const int wr = (w >> 1) * 64, wc = (w & 1) * 32;
    const int lrow = lane >> 3, lcol = (lane & 7) * 8;

    f32x4 acc[4][2];
#pragma unroll
    for (int i = 0; i < 4; i++)
#pragma unroll
        for (int j = 0; j < 2; j++) acc[i][j] = (f32x4){0.f, 0.f, 0.f, 0.f};

    for (int k0 = 0; k0 < 1024; k0 += 64) {
        __syncthreads();
#pragma unroll
        for (int is = 0; is < 4; is++) {
            int r = is * 32 + w * 8 + lrow;
            async_load16(A + (size_t)(mtile + r) * 1024 + k0 + lcol, &As[(is * 32 + w * 8) * 64]);
        }
#pragma unroll
        for (int is = 0; is < 2; is++) {
            int r = is * 32 + w * 8 + lrow;
            async_load16(Bm + (size_t)(ntile + r) * 1024 + k0 + lcol, &Bs[(is * 32 + w * 8) * 64]);
        }
        __syncthreads();
#pragma unroll
        for (int kk = 0; kk < 2; kk++) {
            bf16x8 af[4], bfr[2];
#pragma unroll
            for (int i = 0; i < 4; i++)
                af[i] = *(const bf16x8*)&As[(wr + i * 16 + id) * 64 + kk * 32 + quad * 8];
#pragma unroll
            for (int j = 0; j < 2; j++)
                bfr[j] = *(const bf16x8*)&Bs[(wc + j * 16 + id) * 64 + kk * 32 + quad * 8];
#pragma unroll
            for (int i = 0; i < 4; i++)
#pragma unroll
                for (int j = 0; j < 2; j++)
                    acc[i][j] = __builtin_amdgcn_mfma_f32_16x16x32_bf16(af[i], bfr[j], acc[i][j], 0, 0, 0);
        }
    }

#pragma unroll
    for (int i = 0; i < 4; i++)
#pragma unroll
        for (int j = 0; j < 2; j++) {
            int mbase = mtile + wr + i * 16 + quad * 4;
            int n = ntile + wc + j * 16 + id;
#pragma unroll
            for (int r = 0; r < 4; r++)
                C[(size_t)(mbase + r) * 1024 + n] = acc[i][j][r];
        }
}

// Flash attention, no-max softmax, register-only P path (R5 structure),
// with loop-carried staging pointers + explicitly unrolled 2-buffer pipeline.
__global__ __launch_bounds__(256, 2) void attn_kernel(const u16* __restrict__ q,
                                                      const u16* __restrict__ k2,
                                                      const u16* __restrict__ vT,
                                                      u16* __restrict__ o) {
    __shared__ u16 Ks[2][64 * 64];
    __shared__ u16 Vt[2][64 * 64];
    const int tid = threadIdx.x;
    const int w = tid >> 6, lane = tid & 63, quad = lane >> 4, id = lane & 15;

    const int bid = blockIdx.x;
    const int xcd = bid & 7, slot = bid >> 3;
    const int bg = xcd * 2 + (slot >> 5);
    const int inner = slot & 31;
    const int b = bg >> 2, g = bg & 3;
    const int h = g * 4 + (inner >> 3);
    const int s0 = (inner & 7) * 128;

    const int stgswz = (((lane & 7) ^ (lane >> 3) ^ ((w & 1) << 2))) * 8;
    int kfkey[2];
#pragma unroll
    for (int c = 0; c < 2; c++)
        kfkey[c] = (id & 3) | (((c ^ ((id >> 2) & 1)) & 1) << 2);
    const int vkey = (id & 7) ^ (((id >> 3) & 1) << 2);
    const int trow_base = ((id & 12) << 1) + (id & 3);

    bf16x8 qf[2][2];
#pragma unroll
    for (int rb = 0; rb < 2; rb++) {
        const size_t base = ((size_t)(b * 1024 + s0 + w * 32 + rb * 16 + id)) * 1024 + h * 64;
        qf[rb][0] = *(const bf16x8*)&q[base + quad * 8];
        qf[rb][1] = *(const bf16x8*)&q[base + 32 + quad * 8];
    }

    bf16x8 ones;
    {
        __bf16 one = (__bf16)1.0f;
#pragma unroll
        for (int i = 0; i < 8; i++) ones[i] = one;
    }

    f32x4 acc[2][4], accl[2];
#pragma unroll
    for (int rb = 0; rb < 2; rb++) {
        accl[rb] = (f32x4){0.f, 0.f, 0.f, 0.f};
#pragma unroll
        for (int i = 0; i < 4; i++) acc[rb][i] = (f32x4){0.f, 0.f, 0.f, 0.f};
    }

    // loop-carried staging pointers (constant strides per chunk)
    const u16* kp = k2 + ((size_t)(b * 4 + g)) * 2048 * 64
                  + (size_t)(w * 8 + (lane >> 3)) * 64 + stgswz;
    const u16* vp = vT + ((size_t)(b * 4 + g)) * 64 * 2048
                  + (size_t)(w * 8 + (lane >> 3)) * 2048 + stgswz;

    auto stage = [&](int buf) {
        async_load16(kp,             &Ks[buf][(w * 8) * 64]);
        async_load16(kp + 32 * 64,   &Ks[buf][(32 + w * 8) * 64]);
        async_load16(vp,             &Vt[buf][(w * 8) * 64]);
        async_load16(vp + 32 * 2048, &Vt[buf][(32 + w * 8) * 64]);
        kp += 64 * 64;
        vp += 64;
    };

    auto process = [&](const u16* Ksb, const u16* Vtb) {
        f32x4 s[2][2][2];
#pragma unroll
        for (int kk = 0; kk < 2; kk++)
#pragma unroll
            for (int P = 0; P < 2; P++)
#pragma unroll
                for (int c = 0; c < 2; c++) {
                    int trow = P * 32 + trow_base + c * 4;
                    bf16x8 kf = *(const bf16x8*)&Ksb[trow * 64 + (((kk * 4 + quad) ^ kfkey[c]) * 8)];
#pragma unroll
                    for (int rb = 0; rb < 2; rb++)
                        s[rb][P][c] = __builtin_amdgcn_mfma_f32_16x16x32_bf16(
                            kf, qf[rb][kk],
                            kk ? s[rb][P][c] : (f32x4){0.f, 0.f, 0.f, 0.f}, 0, 0, 0);
                }

        bf16x8 pa[2][2];
#pragma unroll
        for (int rb = 0; rb < 2; rb++)
#pragma unroll
            for (int P = 0; P < 2; P++) {
                bf16x8 t;
#pragma unroll
                for (int c = 0; c < 2; c++)
#pragma unroll
                    for (int r = 0; r < 4; r++)
                        t[c * 4 + r] = (__bf16)__builtin_exp2f(s[rb][P][c][r]);
                pa[rb][P] = t;
            }

#pragma unroll
        for (int P = 0; P < 2; P++) {
#pragma unroll
            for (int db = 0; db < 4; db++) {
                bf16x8 vf = *(const bf16x8*)&Vtb[(db * 16 + id) * 64 + (((P * 4 + quad) ^ vkey) * 8)];
#pragma unroll
                for (int rb = 0; rb < 2; rb++)
                    acc[rb][db] = __builtin_amdgcn_mfma_f32_16x16x32_bf16(pa[rb][P], vf, acc[rb][db], 0, 0, 0);
            }
#pragma unroll
            for (int rb = 0; rb < 2; rb++)
                accl[rb] = __builtin_amdgcn_mfma_f32_16x16x32_bf16(pa[rb][P], ones, accl[rb], 0, 0, 0);
        }
    };

    stage(0);
    __syncthreads();

#pragma unroll 1
    for (int it = 0; it < 16; ++it) {
        stage(1);                      // chunk 2it+1, overlaps buf0 compute
        process(Ks[0], Vt[0]);
        __syncthreads();
        if (it != 15) stage(0);        // chunk 2it+2, overlaps buf1 compute
        process(Ks[1], Vt[1]);
        __syncthreads();
    }

    // normalize + store
#pragma unroll
    for (int rb = 0; rb < 2; rb++) {
        f32x4 inv;
#pragma unroll
        for (int r = 0; r < 4; r++) inv[r] = 1.0f / accl[rb][r];
#pragma unroll
        for (int db = 0; db < 4; db++)
#pragma unroll
            for (int r = 0; r < 4; r++) {
                int srow = s0 + w * 32 + rb * 16 + quad * 4 + r;
                o[((size_t)(b * 1024 + srow)) * 1024 + h * 64 + db * 16 + id] =
                    f2bfbits(acc[rb][db][r] * inv[r]);
            }
    }
}

extern "C" void kernel_launch(void* const* d_in, const int* in_sizes, int n_in,
                              void* d_out, int out_size, void* d_ws, size_t ws_size,
                              hipStream_t stream) {
    (void)in_sizes; (void)n_in; (void)out_size; (void)ws_size;
    const float* x   = (const float*)d_in[0];
    const float* ctx = (const float*)d_in[1];
    const float* Wq  = (const float*)d_in[2];
    const float* Wk  = (const float*)d_in[3];
    const float* Wv  = (const float*)d_in[4];
    const float* Wo  = (const float*)d_in[5];
    float* out = (float*)d_out;

    u16* xb   = (u16*)d_ws;
    u16* ctxb = xb   + 4096 * 1024;
    u16* Wqb  = ctxb + 4 * 2048 * 1024;
    u16* Wkb  = Wqb  + 1024 * 1024;
    u16* Wvb  = Wkb  + 256 * 1024;
    u16* Wob  = Wvb  + 256 * 1024;
    u16* q    = Wob  + 1024 * 1024;
    u16* k2   = q    + 4096 * 1024;
    u16* vT   = k2   + 4 * 4 * 2048 * 64;
    u16* o    = vT   + 4 * 4 * 64 * 2048;

    convert_all<<<7424, 256, 0, stream>>>(x, ctx, Wq, Wk, Wv, Wo,
                                          xb, ctxb, Wqb, Wkb, Wvb, Wob);
    proj_qkv<<<1024, 256, 0, stream>>>(xb, ctxb, Wqb, Wkb, Wvb, q, k2, vT);
    attn_kernel<<<512, 256, 0, stream>>>(q, k2, vT, o);
    gemm_out<<<dim3(16, 32), 256, 0, stream>>>(o, Wob, out);
}